// Round 6
// baseline (55.019 us; speedup 1.0000x reference)
//
#include <hip/hip_runtime.h>

#define UNITS 256
#define BATCH 256

typedef float fx4 __attribute__((ext_vector_type(4)));

// Kernel 1: pure zeroing of out[256][256] (atomic flush target). 256KB.
__global__ __launch_bounds__(256) void k_zero(float* __restrict__ out) {
    const int i = (blockIdx.x * 256 + threadIdx.x) << 2;
    *reinterpret_cast<fx4*>(out + i) = fx4{0.f, 0.f, 0.f, 0.f};
}

// Kernel 2: chunked accumulation, contiguous-per-wave streams.
// - 2-barrier shfl_up scan of segment sizes -> s_ends (proven R5).
// - Balanced two-tier chunking over exactly 2048 blocks (all co-resident:
//   256 CU x 8 blocks/CU; __launch_bounds__(256,8) pins VGPR<=64).
// - Wave rl owns contiguous rows [r0+rl*wq, r0+(rl+1)*wq): fully SEQUENTIAL
//   1KB row reads (vs R5's 4KB-strided interleave) -> 32 sequential streams
//   per CU; unrolled x4 loads use 1024/2048/3072-byte immediates (one base
//   update per 4 loads).
// - wq <= 34 < 100 = min segment -> each wave crosses <=1 boundary -> 2 run
//   slots; block spans <=3 consecutive segments.
// - ONE barrier + one merged flush per block: per-thread static 3-slot merge
//   (slot = seg - seg0), <=3 scaled atomics/thread (divide folded in).
__global__ __launch_bounds__(256, 8) void k_accum(const float* __restrict__ x,
                                                  const int* __restrict__ nclasses,
                                                  const int* __restrict__ nfeature,
                                                  float* __restrict__ out,
                                                  int total_rows, int lo, int nE4) {
    __shared__ int   s_ends[BATCH];
    __shared__ float s_inv[BATCH];
    __shared__ int   s_wsum[4];
    __shared__ int   s_seg[4][2];
    __shared__ float s_red[4][2][256];
    const int t  = threadIdx.x;
    const int ln = t & 63;
    const int rl = t >> 6;

    // ---- 2-barrier inclusive scan of sizes -> s_ends ----
    {
        const int sz = nclasses[t] * nfeature[t];
        s_inv[t] = 1.0f / (float)sz;
        int v = sz;
        #pragma unroll
        for (int off = 1; off < 64; off <<= 1) {
            int u = __shfl_up(v, off, 64);
            if (ln >= off) v += u;
        }
        if (ln == 63) s_wsum[rl] = v;
        __syncthreads();
        int base = 0;
        #pragma unroll
        for (int w = 0; w < 3; ++w)
            if (w < rl) base += s_wsum[w];
        s_ends[t] = v + base;
        __syncthreads();
    }

    // ---- balanced chunk geometry ----
    const int b    = blockIdx.x;
    const int hi   = lo + 4;
    const int r0   = (b < nE4) ? b * hi : nE4 * hi + (b - nE4) * lo;
    const int csz  = (b < nE4) ? hi : lo;
    const int rend = min(r0 + csz, total_rows);
    if (r0 >= rend) return;               // block-uniform

    // wave-contiguous sub-ranges
    const int wq = csz >> 2;              // csz is a multiple of 4
    const int ws = min(r0 + rl * wq, rend);
    const int we = min(r0 + (rl + 1) * wq, rend);

    // wave-uniform binary search: first segment with end > ws
    const int key = min(ws, rend - 1);
    int slo = 0, shi = BATCH;
    while (slo < shi) {
        int mid = (slo + shi) >> 1;
        if (s_ends[mid] > key) shi = mid; else slo = mid + 1;
    }
    int seg = slo;

    const float* p = x + (size_t)ws * UNITS + (ln << 2);
    int r = ws;
    fx4 acc = {0.f, 0.f, 0.f, 0.f};

    #pragma unroll
    for (int run = 0; run < 2; ++run) {
        const int stop = min(s_ends[seg], we);
        int cnt = stop - r;               // rows this wave, this run
        if (cnt < 0) cnt = 0;
        r += cnt;

        int k = 0;
        for (; k + 4 <= cnt; k += 4) {    // 4 sequential rows: imm offsets
            fx4 v0 = *(const fx4*)(p);
            fx4 v1 = *(const fx4*)(p + UNITS);
            fx4 v2 = *(const fx4*)(p + 2 * UNITS);
            fx4 v3 = *(const fx4*)(p + 3 * UNITS);
            p += 4 * UNITS;
            acc += (v0 + v1) + (v2 + v3);
        }
        for (; k < cnt; ++k) {
            fx4 v = *(const fx4*)(p);
            p += UNITS;
            acc += v;
        }

        if (ln == 0) s_seg[rl][run] = seg;
        *reinterpret_cast<fx4*>(&s_red[rl][run][ln << 2]) = acc;
        acc = fx4{0.f, 0.f, 0.f, 0.f};
        if (r < we) ++seg;                // advance only while rows remain
    }
    __syncthreads();

    // ---- merged flush: static 3-slot per-thread reduce, <=3 atomics ----
    {
        const int seg0 = s_seg[0][0];     // block's first segment (wave 0 @ r0)
        float a0 = 0.f, a1 = 0.f, a2 = 0.f;
        int maxd = 0;
        #pragma unroll
        for (int w = 0; w < 4; ++w) {
            #pragma unroll
            for (int run = 0; run < 2; ++run) {
                const int d = s_seg[w][run] - seg0;   // 0..2, block-uniform
                const float v = s_red[w][run][t];
                a0 += (d == 0) ? v : 0.f;
                a1 += (d == 1) ? v : 0.f;
                a2 += (d == 2) ? v : 0.f;
                maxd = max(maxd, d);
            }
        }
        unsafeAtomicAdd(out + seg0 * UNITS + t, a0 * s_inv[seg0]);
        if (maxd >= 1)
            unsafeAtomicAdd(out + (seg0 + 1) * UNITS + t, a1 * s_inv[seg0 + 1]);
        if (maxd >= 2)
            unsafeAtomicAdd(out + (seg0 + 2) * UNITS + t, a2 * s_inv[seg0 + 2]);
    }
}

extern "C" void kernel_launch(void* const* d_in, const int* in_sizes, int n_in,
                              void* d_out, int out_size, void* d_ws, size_t ws_size,
                              hipStream_t stream) {
    const float* x        = (const float*)d_in[0];
    const int*   nclasses = (const int*)d_in[1];
    const int*   nfeature = (const int*)d_in[2];
    float*       out      = (float*)d_out;

    const int total_rows = in_sizes[0] / UNITS;

    // balanced two-tier chunking over exactly 2048 blocks
    const int q   = total_rows >> 11;         // total/2048
    const int lo  = q & ~3;                   // lower chunk, multiple of 4
    const int E   = total_rows - (lo << 11);  // leftover rows
    const int nE4 = (E + 3) >> 2;             // blocks that take lo+4 rows

    k_zero<<<64, 256, 0, stream>>>(out);
    k_accum<<<2048, 256, 0, stream>>>(x, nclasses, nfeature, out,
                                      total_rows, lo, nE4);
}